// Round 1
// baseline (17802.382 us; speedup 1.0000x reference)
//
#include <hip/hip_runtime.h>
#include <math.h>

#define NNODES 50000
#define NEDGES 800000
#define D 128
#define NEG_SLOPE 0.2f
#define BN_EPS 1e-5f

// ---- order-preserving float<->uint encoding for atomicMax on floats ----
__device__ __forceinline__ unsigned encF(float x) {
  unsigned b = __float_as_uint(x);
  return (b & 0x80000000u) ? ~b : (b | 0x80000000u);
}
__device__ __forceinline__ float decF(unsigned u) {
  unsigned b = (u & 0x80000000u) ? (u ^ 0x80000000u) : ~u;
  return __uint_as_float(b);
}

// xl = x @ Wl, xr = x @ Wr.  W row-major [K=128][N=128].
// Block: 256 threads = cols 0..127 -> xl, 128..255 -> xr. 32 rows per block.
// x reads are wave-uniform -> scalar loads; W reads coalesced, L1/L2-resident.
__global__ __launch_bounds__(256) void k_gemm(const float* __restrict__ x,
        const float* __restrict__ Wl, const float* __restrict__ Wr,
        float* __restrict__ xl, float* __restrict__ xr, int n) {
  const int t = threadIdx.x;
  const int col = t & 127;
  const float* __restrict__ W = (t < 128) ? Wl : Wr;
  float* __restrict__ outp = (t < 128) ? xl : xr;
  const int row0 = blockIdx.x * 32;

  int rows[32];
#pragma unroll
  for (int r = 0; r < 32; ++r) {
    int row = row0 + r;
    rows[r] = (row < n ? row : n - 1) * D;
  }
  float acc[32];
#pragma unroll
  for (int r = 0; r < 32; ++r) acc[r] = 0.f;

  for (int k = 0; k < D; ++k) {
    float w = W[k * D + col];
#pragma unroll
    for (int r = 0; r < 32; ++r) {
      acc[r] += x[rows[r] + k] * w;
    }
  }
#pragma unroll
  for (int r = 0; r < 32; ++r) {
    int row = row0 + r;
    if (row < n) outp[(size_t)row * D + col] = acc[r];
  }
}

// per-edge attention score e = leaky_relu(xl[src]+xr[dst]) . att ; segment max via atomicMax
__global__ __launch_bounds__(256) void k_edge_score(const float* __restrict__ xl,
        const float* __restrict__ xr, const int* __restrict__ src,
        const int* __restrict__ dst, const float* __restrict__ att,
        float* __restrict__ esc, unsigned* __restrict__ emax, int E) {
  int e = blockIdx.x * 256 + threadIdx.x;
  if (e >= E) return;
  int s = src[e], d = dst[e];
  const float4* a4 = (const float4*)(xl + (size_t)s * D);
  const float4* b4 = (const float4*)(xr + (size_t)d * D);
  const float4* t4 = (const float4*)att;
  float acc = 0.f;
#pragma unroll
  for (int k = 0; k < D / 4; ++k) {
    float4 a = a4[k], b = b4[k], w = t4[k];
    float v0 = a.x + b.x; v0 = v0 > 0.f ? v0 : NEG_SLOPE * v0;
    float v1 = a.y + b.y; v1 = v1 > 0.f ? v1 : NEG_SLOPE * v1;
    float v2 = a.z + b.z; v2 = v2 > 0.f ? v2 : NEG_SLOPE * v2;
    float v3 = a.w + b.w; v3 = v3 > 0.f ? v3 : NEG_SLOPE * v3;
    acc += v0 * w.x + v1 * w.y + v2 * w.z + v3 * w.w;
  }
  esc[e] = acc;
  atomicMax(&emax[d], encF(acc));
}

// a = exp(e - emax[dst]); denom[dst] += a
__global__ __launch_bounds__(256) void k_edge_exp(float* __restrict__ esc,
        const int* __restrict__ dst, const unsigned* __restrict__ emax,
        float* __restrict__ denom, int E) {
  int e = blockIdx.x * 256 + threadIdx.x;
  if (e >= E) return;
  int d = dst[e];
  float a = __expf(esc[e] - decF(emax[d]));
  esc[e] = a;
  atomicAdd(&denom[d], a);
}

// out[dst] += (a/denom) * xl[src]
__global__ __launch_bounds__(256) void k_edge_agg(const float* __restrict__ esc,
        const float* __restrict__ xl, const int* __restrict__ src,
        const int* __restrict__ dst, const float* __restrict__ denom,
        float* __restrict__ agg, int E) {
  int e = blockIdx.x * 256 + threadIdx.x;
  if (e >= E) return;
  int s = src[e], d = dst[e];
  float alpha = esc[e] / (denom[d] + 1e-16f);
  const float4* a4 = (const float4*)(xl + (size_t)s * D);
  float* o = agg + (size_t)d * D;
#pragma unroll
  for (int k = 0; k < D / 4; ++k) {
    float4 a = a4[k];
    atomicAdd(o + 4 * k + 0, alpha * a.x);
    atomicAdd(o + 4 * k + 1, alpha * a.y);
    atomicAdd(o + 4 * k + 2, alpha * a.z);
    atomicAdd(o + 4 * k + 3, alpha * a.w);
  }
}

// per-channel partial sums of v and v^2
__global__ __launch_bounds__(256) void k_bn_stats(const float* __restrict__ agg,
        float* __restrict__ sums, int n) {
  int c = threadIdx.x & 127;
  int half = threadIdx.x >> 7;
  float s = 0.f, s2 = 0.f;
  for (int r = blockIdx.x * 2 + half; r < n; r += gridDim.x * 2) {
    float v = agg[(size_t)r * D + c];
    s += v;
    s2 += v * v;
  }
  atomicAdd(&sums[c], s);
  atomicAdd(&sums[D + c], s2);
}

__global__ void k_bn_fin(const float* __restrict__ sums, const float* __restrict__ gamma,
        const float* __restrict__ beta, float* __restrict__ ss, float inv_n) {
  int c = threadIdx.x;
  float mu = sums[c] * inv_n;
  float var = sums[D + c] * inv_n - mu * mu;
  float rs = rsqrtf(var + BN_EPS);
  float sc = gamma[c] * rs;
  ss[c] = sc;
  ss[D + c] = beta[c] - mu * sc;
}

// y = gelu_exact(scale*v + shift), in-place capable
__global__ __launch_bounds__(256) void k_bn_apply(const float* __restrict__ agg,
        const float* __restrict__ ss, float* __restrict__ xo, int total4) {
  int i = blockIdx.x * 256 + threadIdx.x;
  if (i >= total4) return;
  float4 v = ((const float4*)agg)[i];
  int c4 = i & (D / 4 - 1);
  float4 sc = ((const float4*)ss)[c4];
  float4 sh = ((const float4*)ss)[D / 4 + c4];
  float y0 = sc.x * v.x + sh.x;
  float y1 = sc.y * v.y + sh.y;
  float y2 = sc.z * v.z + sh.z;
  float y3 = sc.w * v.w + sh.w;
  float4 g;
  g.x = 0.5f * y0 * (1.f + erff(y0 * 0.70710678118654752f));
  g.y = 0.5f * y1 * (1.f + erff(y1 * 0.70710678118654752f));
  g.z = 0.5f * y2 * (1.f + erff(y2 * 0.70710678118654752f));
  g.w = 0.5f * y3 * (1.f + erff(y3 * 0.70710678118654752f));
  ((float4*)xo)[i] = g;
}

extern "C" void kernel_launch(void* const* d_in, const int* in_sizes, int n_in,
                              void* d_out, int out_size, void* d_ws, size_t ws_size,
                              hipStream_t stream) {
  const float* x0    = (const float*)d_in[0];
  const int*   ei    = (const int*)d_in[1];
  const float* Wl    = (const float*)d_in[2];
  const float* Wr    = (const float*)d_in[3];
  const float* att   = (const float*)d_in[4];
  // d_in[5] = bias: exactly cancelled by BatchNorm mean-subtraction; unused.
  const float* gamma = (const float*)d_in[6];
  const float* beta  = (const float*)d_in[7];
  float* out = (float*)d_out;

  float* ws = (float*)d_ws;
  float*    xl    = ws;                       // 6.4M
  float*    xr    = ws + 6400000;             // 6.4M
  float*    buf   = ws + 12800000;            // 6.4M (ping-pong x buffer)
  float*    esc   = ws + 19200000;            // 800k
  unsigned* emax  = (unsigned*)(ws + 20000000); // 50k
  float*    denom = ws + 20050000;            // 50k
  float*    sums  = ws + 20100000;            // 256
  float*    ss    = ws + 20100256;            // 256

  const int* src = ei;
  const int* dst = ei + NEDGES;

  for (int l = 0; l < 3; ++l) {
    const float* xin = (l == 0) ? x0 : buf;
    float* agg = (l == 2) ? out : buf;

    k_gemm<<<(NNODES + 31) / 32, 256, 0, stream>>>(xin, Wl + l * D * D, Wr + l * D * D,
                                                   xl, xr, NNODES);
    // agg may alias xin(=buf); the memset is stream-ordered after k_gemm.
    hipMemsetAsync(emax, 0, NNODES * sizeof(unsigned), stream);
    hipMemsetAsync(denom, 0, NNODES * sizeof(float), stream);
    hipMemsetAsync(agg, 0, (size_t)NNODES * D * sizeof(float), stream);
    hipMemsetAsync(sums, 0, 2 * D * sizeof(float), stream);

    k_edge_score<<<(NEDGES + 255) / 256, 256, 0, stream>>>(xl, xr, src, dst,
                                                           att + l * D, esc, emax, NEDGES);
    k_edge_exp<<<(NEDGES + 255) / 256, 256, 0, stream>>>(esc, dst, emax, denom, NEDGES);
    k_edge_agg<<<(NEDGES + 255) / 256, 256, 0, stream>>>(esc, xl, src, dst, denom, agg, NEDGES);

    k_bn_stats<<<512, 256, 0, stream>>>(agg, sums, NNODES);
    k_bn_fin<<<1, D, 0, stream>>>(sums, gamma + l * D, beta + l * D, ss, 1.0f / NNODES);
    k_bn_apply<<<(NNODES * (D / 4) + 255) / 256, 256, 0, stream>>>(agg, ss, agg, NNODES * (D / 4));
  }
}

// Round 2
// 1996.246 us; speedup vs baseline: 8.9179x; 8.9179x over previous
//
#include <hip/hip_runtime.h>
#include <math.h>

#define NNODES 50000
#define NEDGES 800000
#define D 128
#define NEG_SLOPE 0.2f
#define BN_EPS 1e-5f

// ============ CSR build (once per call; edge_index is layer-invariant) ======

__global__ __launch_bounds__(256) void k_hist(const int* __restrict__ dst,
        int* __restrict__ counts, int E) {
  int e = blockIdx.x * 256 + threadIdx.x;
  if (e < E) atomicAdd(&counts[dst[e]], 1);
}

// single-block sequential chunked scan of counts[0..n) -> row_ptr[0..n]
__global__ void k_scan(const int* __restrict__ counts, int* __restrict__ row_ptr, int n) {
  __shared__ int lds[256];
  __shared__ int running;
  int t = threadIdx.x;
  if (t == 0) { running = 0; row_ptr[0] = 0; }
  __syncthreads();
  for (int base = 0; base < n; base += 256) {
    int v = (base + t < n) ? counts[base + t] : 0;
    lds[t] = v;
    __syncthreads();
    for (int off = 1; off < 256; off <<= 1) {
      int u = (t >= off) ? lds[t - off] : 0;
      __syncthreads();
      lds[t] += u;
      __syncthreads();
    }
    if (base + t < n) row_ptr[base + t + 1] = running + lds[t];
    __syncthreads();
    if (t == 0) running += lds[255];
    __syncthreads();
  }
}

__global__ __launch_bounds__(256) void k_scatter(const int* __restrict__ src,
        const int* __restrict__ dst, int* __restrict__ cursor,
        int* __restrict__ col_src, int* __restrict__ col_dst, int E) {
  int e = blockIdx.x * 256 + threadIdx.x;
  if (e >= E) return;
  int s = src[e], d = dst[e];
  int slot = atomicAdd(&cursor[d], 1);
  col_src[slot] = s;
  col_dst[slot] = d;
}

// ============ per-layer kernels ============================================

// xl = x @ Wl, xr = x @ Wr.  W row-major [K=128][N=128].
__global__ __launch_bounds__(256) void k_gemm(const float* __restrict__ x,
        const float* __restrict__ Wl, const float* __restrict__ Wr,
        float* __restrict__ xl, float* __restrict__ xr, int n) {
  const int t = threadIdx.x;
  const int col = t & 127;
  const float* __restrict__ W = (t < 128) ? Wl : Wr;
  float* __restrict__ outp = (t < 128) ? xl : xr;
  const int row0 = blockIdx.x * 32;

  int rows[32];
#pragma unroll
  for (int r = 0; r < 32; ++r) {
    int row = row0 + r;
    rows[r] = (row < n ? row : n - 1) * D;
  }
  float acc[32];
#pragma unroll
  for (int r = 0; r < 32; ++r) acc[r] = 0.f;

  for (int k = 0; k < D; ++k) {
    float w = W[k * D + col];
#pragma unroll
    for (int r = 0; r < 32; ++r) {
      acc[r] += x[rows[r] + k] * w;
    }
  }
#pragma unroll
  for (int r = 0; r < 32; ++r) {
    int row = row0 + r;
    if (row < n) outp[(size_t)row * D + col] = acc[r];
  }
}

// raw score per CSR slot: esc[k] = leaky_relu(xl[src]+xr[dst]) . att
// slots sorted by dst -> xr reads L1-local; no atomics.
__global__ __launch_bounds__(256) void k_edge_score(const float* __restrict__ xl,
        const float* __restrict__ xr, const int* __restrict__ col_src,
        const int* __restrict__ col_dst, const float* __restrict__ att,
        float* __restrict__ esc, int E) {
  int e = blockIdx.x * 256 + threadIdx.x;
  if (e >= E) return;
  int s = col_src[e], d = col_dst[e];
  const float4* a4 = (const float4*)(xl + (size_t)s * D);
  const float4* b4 = (const float4*)(xr + (size_t)d * D);
  const float4* t4 = (const float4*)att;
  float acc = 0.f;
#pragma unroll
  for (int k = 0; k < D / 4; ++k) {
    float4 a = a4[k], b = b4[k], w = t4[k];
    float v0 = a.x + b.x; v0 = v0 > 0.f ? v0 : NEG_SLOPE * v0;
    float v1 = a.y + b.y; v1 = v1 > 0.f ? v1 : NEG_SLOPE * v1;
    float v2 = a.z + b.z; v2 = v2 > 0.f ? v2 : NEG_SLOPE * v2;
    float v3 = a.w + b.w; v3 = v3 > 0.f ? v3 : NEG_SLOPE * v3;
    acc += v0 * w.x + v1 * w.y + v2 * w.z + v3 * w.w;
  }
  esc[e] = acc;
}

// fused per-node softmax + gather-aggregate. One wave per node, float2/lane.
// out[d] = sum_k exp(e_k - m) * xl[src_k] / sum_k exp(e_k - m)
__global__ __launch_bounds__(256) void k_agg(const float* __restrict__ esc,
        const float* __restrict__ xl, const int* __restrict__ col_src,
        const int* __restrict__ row_ptr, float* __restrict__ out, int n) {
  int node = blockIdx.x * 4 + (threadIdx.x >> 6);
  if (node >= n) return;
  int c = threadIdx.x & 63;
  int k0 = row_ptr[node], k1 = row_ptr[node + 1];
  float m = -1e30f;
  for (int k = k0; k < k1; ++k) m = fmaxf(m, esc[k]);
  float ax = 0.f, ay = 0.f, den = 0.f;
  const float2* xl2 = (const float2*)xl;
  for (int k = k0; k < k1; ++k) {
    float a = __expf(esc[k] - m);
    den += a;
    int s = col_src[k];
    float2 v = xl2[(size_t)s * (D / 2) + c];
    ax += a * v.x;
    ay += a * v.y;
  }
  float inv = 1.f / (den + 1e-16f);
  ((float2*)out)[(size_t)node * (D / 2) + c] = make_float2(ax * inv, ay * inv);
}

// ============ BatchNorm + GELU =============================================

__global__ __launch_bounds__(256) void k_bn_stats(const float* __restrict__ agg,
        float* __restrict__ sums, int n) {
  int c = threadIdx.x & 127;
  int half = threadIdx.x >> 7;
  float s = 0.f, s2 = 0.f;
  for (int r = blockIdx.x * 2 + half; r < n; r += gridDim.x * 2) {
    float v = agg[(size_t)r * D + c];
    s += v;
    s2 += v * v;
  }
  atomicAdd(&sums[c], s);
  atomicAdd(&sums[D + c], s2);
}

__global__ void k_bn_fin(const float* __restrict__ sums, const float* __restrict__ gamma,
        const float* __restrict__ beta, float* __restrict__ ss, float inv_n) {
  int c = threadIdx.x;
  float mu = sums[c] * inv_n;
  float var = sums[D + c] * inv_n - mu * mu;
  float rs = rsqrtf(var + BN_EPS);
  float sc = gamma[c] * rs;
  ss[c] = sc;
  ss[D + c] = beta[c] - mu * sc;
}

__global__ __launch_bounds__(256) void k_bn_apply(const float* __restrict__ agg,
        const float* __restrict__ ss, float* __restrict__ xo, int total4) {
  int i = blockIdx.x * 256 + threadIdx.x;
  if (i >= total4) return;
  float4 v = ((const float4*)agg)[i];
  int c4 = i & (D / 4 - 1);
  float4 sc = ((const float4*)ss)[c4];
  float4 sh = ((const float4*)ss)[D / 4 + c4];
  float y0 = sc.x * v.x + sh.x;
  float y1 = sc.y * v.y + sh.y;
  float y2 = sc.z * v.z + sh.z;
  float y3 = sc.w * v.w + sh.w;
  float4 g;
  g.x = 0.5f * y0 * (1.f + erff(y0 * 0.70710678118654752f));
  g.y = 0.5f * y1 * (1.f + erff(y1 * 0.70710678118654752f));
  g.z = 0.5f * y2 * (1.f + erff(y2 * 0.70710678118654752f));
  g.w = 0.5f * y3 * (1.f + erff(y3 * 0.70710678118654752f));
  ((float4*)xo)[i] = g;
}

// ===========================================================================

extern "C" void kernel_launch(void* const* d_in, const int* in_sizes, int n_in,
                              void* d_out, int out_size, void* d_ws, size_t ws_size,
                              hipStream_t stream) {
  const float* x0    = (const float*)d_in[0];
  const int*   ei    = (const int*)d_in[1];
  const float* Wl    = (const float*)d_in[2];
  const float* Wr    = (const float*)d_in[3];
  const float* att   = (const float*)d_in[4];
  // d_in[5] = bias: cancelled exactly by BatchNorm mean-subtraction; unused.
  const float* gamma = (const float*)d_in[6];
  const float* beta  = (const float*)d_in[7];
  float* out = (float*)d_out;

  float* ws = (float*)d_ws;
  float* xl      = ws;                          // 6,400,000
  float* xr      = ws + 6400000;                // 6,400,000
  float* esc     = ws + 12800000;               //   800,000
  int*   col_src = (int*)(ws + 13600000);       //   800,000
  int*   col_dst = (int*)(ws + 14400000);       //   800,000
  int*   row_ptr = (int*)(ws + 15200000);       //    50,001
  int*   cursor  = (int*)(ws + 15250004);       //    50,000
  int*   counts  = (int*)(ws + 15300004);       //    50,000
  float* sums    = ws + 15350004;               //       256
  float* ss      = ws + 15350260;               //       256

  const int* src = ei;
  const int* dst = ei + NEDGES;

  // ---- build CSR by destination (once; reused for all 3 layers) ----
  hipMemsetAsync(counts, 0, NNODES * sizeof(int), stream);
  k_hist<<<(NEDGES + 255) / 256, 256, 0, stream>>>(dst, counts, NEDGES);
  k_scan<<<1, 256, 0, stream>>>(counts, row_ptr, NNODES);
  hipMemcpyAsync(cursor, row_ptr, NNODES * sizeof(int), hipMemcpyDeviceToDevice, stream);
  k_scatter<<<(NEDGES + 255) / 256, 256, 0, stream>>>(src, dst, cursor, col_src, col_dst, NEDGES);

  for (int l = 0; l < 3; ++l) {
    const float* xin = (l == 0) ? x0 : out;

    k_gemm<<<(NNODES + 31) / 32, 256, 0, stream>>>(xin, Wl + l * D * D, Wr + l * D * D,
                                                   xl, xr, NNODES);
    hipMemsetAsync(sums, 0, 2 * D * sizeof(float), stream);

    k_edge_score<<<(NEDGES + 255) / 256, 256, 0, stream>>>(xl, xr, col_src, col_dst,
                                                           att + l * D, esc, NEDGES);
    // d_out is dead as an input after k_gemm -> safe to overwrite with agg.
    k_agg<<<(NNODES + 3) / 4, 256, 0, stream>>>(esc, xl, col_src, row_ptr, out, NNODES);

    k_bn_stats<<<512, 256, 0, stream>>>(out, sums, NNODES);
    k_bn_fin<<<1, D, 0, stream>>>(sums, gamma + l * D, beta + l * D, ss, 1.0f / NNODES);
    k_bn_apply<<<(NNODES * (D / 4) + 255) / 256, 256, 0, stream>>>(out, ss, out, NNODES * (D / 4));
  }
}

// Round 3
// 1240.909 us; speedup vs baseline: 14.3462x; 1.6087x over previous
//
#include <hip/hip_runtime.h>
#include <math.h>

#define NNODES 50000
#define NEDGES 800000
#define D 128
#define NEG_SLOPE 0.2f
#define BN_EPS 1e-5f

// ============ CSR build (once per call; edge_index is layer-invariant) ======

__global__ __launch_bounds__(256) void k_hist(const int* __restrict__ dst,
        int* __restrict__ counts, int E) {
  int e = blockIdx.x * 256 + threadIdx.x;
  if (e < E) atomicAdd(&counts[dst[e]], 1);
}

// single-block sequential chunked scan of counts[0..n) -> row_ptr[0..n]
__global__ void k_scan(const int* __restrict__ counts, int* __restrict__ row_ptr, int n) {
  __shared__ int lds[256];
  __shared__ int running;
  int t = threadIdx.x;
  if (t == 0) { running = 0; row_ptr[0] = 0; }
  __syncthreads();
  for (int base = 0; base < n; base += 256) {
    int v = (base + t < n) ? counts[base + t] : 0;
    lds[t] = v;
    __syncthreads();
    for (int off = 1; off < 256; off <<= 1) {
      int u = (t >= off) ? lds[t - off] : 0;
      __syncthreads();
      lds[t] += u;
      __syncthreads();
    }
    if (base + t < n) row_ptr[base + t + 1] = running + lds[t];
    __syncthreads();
    if (t == 0) running += lds[255];
    __syncthreads();
  }
}

__global__ __launch_bounds__(256) void k_scatter(const int* __restrict__ src,
        const int* __restrict__ dst, int* __restrict__ cursor,
        int* __restrict__ col_src, int* __restrict__ col_dst, int E) {
  int e = blockIdx.x * 256 + threadIdx.x;
  if (e >= E) return;
  int s = src[e], d = dst[e];
  int slot = atomicAdd(&cursor[d], 1);
  col_src[slot] = s;
  col_dst[slot] = d;
}

// ============ GEMM: LDS-tiled, register-blocked f32 ========================
// Block tile: 64 rows x 64 cols, 256 threads, 4x4 micro-tile per thread.
// Thread (i = t&15, j = t>>4): rows {i, i+16, i+32, i+48}, cols {4j..4j+3}.
// x tile LDS [64][128] f32, XOR-swizzled (byte ^= (row&7)<<4) against the
// 512B row-stride bank collision on ds_read_b128. W tile [128][64] f32,
// rows contiguous -> reads are 4-address broadcasts, conflict-free.
// grid.y in 0..3 selects {Wl lo, Wl hi, Wr lo, Wr hi}.
__global__ __launch_bounds__(256) void k_gemm(const float* __restrict__ x,
        const float* __restrict__ Wl, const float* __restrict__ Wr,
        float* __restrict__ xl, float* __restrict__ xr, int n) {
  __shared__ float xs[64 * 128];
  __shared__ float wsd[128 * 64];
  const int t = threadIdx.x;
  const int row0 = blockIdx.x * 64;
  const int cb = blockIdx.y;
  const float* __restrict__ Wg = (cb < 2) ? Wl : Wr;
  float* __restrict__ outp = (cb < 2) ? xl : xr;
  const int cbase = (cb & 1) * 64;

  // ---- stage x tile (reg-staged, swizzled ds_write_b128) ----
  {
    int row = t >> 2, qr = t & 3;
    int grow = row0 + row;
    if (grow >= n) grow = n - 1;
    const float4* gp = (const float4*)(x + (size_t)grow * D + qr * 32);
#pragma unroll
    for (int m = 0; m < 8; ++m) {
      float4 v = gp[m];
      int byte = row * 512 + qr * 128 + m * 16;
      byte ^= (row & 7) << 4;
      *(float4*)((char*)xs + byte) = v;
    }
  }
  // ---- stage W tile [128 k][64 c] ----
  {
#pragma unroll
    for (int m = 0; m < 8; ++m) {
      int idx = m * 256 + t;          // float4 index
      int k = idx >> 4, c4 = idx & 15;
      float4 v = *(const float4*)(Wg + k * D + cbase + c4 * 4);
      *(float4*)((char*)wsd + k * 256 + c4 * 16) = v;
    }
  }
  __syncthreads();

  const int i = t & 15;
  const int j = t >> 4;
  float acc[4][4];
#pragma unroll
  for (int r = 0; r < 4; ++r)
#pragma unroll
    for (int c = 0; c < 4; ++c) acc[r][c] = 0.f;

  for (int kc = 0; kc < 32; ++kc) {   // 4 k's per iteration
    float4 xv[4], wv[4];
#pragma unroll
    for (int rr = 0; rr < 4; ++rr) {
      int row = i + rr * 16;
      int byte = (row * 512 + kc * 16) ^ ((row & 7) << 4);
      xv[rr] = *(const float4*)((const char*)xs + byte);
    }
#pragma unroll
    for (int kk = 0; kk < 4; ++kk) {
      wv[kk] = *(const float4*)((const char*)wsd + (kc * 4 + kk) * 256 + j * 16);
    }
#pragma unroll
    for (int rr = 0; rr < 4; ++rr) {
      const float* xr_ = (const float*)&xv[rr];
#pragma unroll
      for (int kk = 0; kk < 4; ++kk) {
        const float* wr_ = (const float*)&wv[kk];
        float xk = xr_[kk];
        acc[rr][0] += xk * wr_[0];
        acc[rr][1] += xk * wr_[1];
        acc[rr][2] += xk * wr_[2];
        acc[rr][3] += xk * wr_[3];
      }
    }
  }

#pragma unroll
  for (int rr = 0; rr < 4; ++rr) {
    int grow = row0 + i + rr * 16;
    if (grow < n) {
      float4 v = make_float4(acc[rr][0], acc[rr][1], acc[rr][2], acc[rr][3]);
      *(float4*)(outp + (size_t)grow * D + cbase + j * 4) = v;
    }
  }
}

// ============ edge kernels =================================================

// raw score per CSR slot: esc[k] = leaky_relu(xl[src]+xr[dst]) . att
__global__ __launch_bounds__(256) void k_edge_score(const float* __restrict__ xl,
        const float* __restrict__ xr, const int* __restrict__ col_src,
        const int* __restrict__ col_dst, const float* __restrict__ att,
        float* __restrict__ esc, int E) {
  int e = blockIdx.x * 256 + threadIdx.x;
  if (e >= E) return;
  int s = col_src[e], d = col_dst[e];
  const float4* a4 = (const float4*)(xl + (size_t)s * D);
  const float4* b4 = (const float4*)(xr + (size_t)d * D);
  const float4* t4 = (const float4*)att;
  float acc = 0.f;
#pragma unroll
  for (int k = 0; k < D / 4; ++k) {
    float4 a = a4[k], b = b4[k], w = t4[k];
    float v0 = a.x + b.x; v0 = v0 > 0.f ? v0 : NEG_SLOPE * v0;
    float v1 = a.y + b.y; v1 = v1 > 0.f ? v1 : NEG_SLOPE * v1;
    float v2 = a.z + b.z; v2 = v2 > 0.f ? v2 : NEG_SLOPE * v2;
    float v3 = a.w + b.w; v3 = v3 > 0.f ? v3 : NEG_SLOPE * v3;
    acc += v0 * w.x + v1 * w.y + v2 * w.z + v3 * w.w;
  }
  esc[e] = acc;
}

// fused per-node softmax + gather-aggregate. One wave per node, float2/lane.
__global__ __launch_bounds__(256) void k_agg(const float* __restrict__ esc,
        const float* __restrict__ xl, const int* __restrict__ col_src,
        const int* __restrict__ row_ptr, float* __restrict__ out, int n) {
  int node = blockIdx.x * 4 + (threadIdx.x >> 6);
  if (node >= n) return;
  int c = threadIdx.x & 63;
  int k0 = row_ptr[node], k1 = row_ptr[node + 1];
  float m = -1e30f;
  for (int k = k0; k < k1; ++k) m = fmaxf(m, esc[k]);
  float ax = 0.f, ay = 0.f, den = 0.f;
  const float2* xl2 = (const float2*)xl;
  for (int k = k0; k < k1; ++k) {
    float a = __expf(esc[k] - m);
    den += a;
    int s = col_src[k];
    float2 v = xl2[(size_t)s * (D / 2) + c];
    ax += a * v.x;
    ay += a * v.y;
  }
  float inv = 1.f / (den + 1e-16f);
  ((float2*)out)[(size_t)node * (D / 2) + c] = make_float2(ax * inv, ay * inv);
}

// ============ BatchNorm + GELU =============================================

__global__ __launch_bounds__(256) void k_bn_stats(const float* __restrict__ agg,
        float* __restrict__ sums, int n) {
  int c = threadIdx.x & 127;
  int half = threadIdx.x >> 7;
  float s = 0.f, s2 = 0.f;
  for (int r = blockIdx.x * 2 + half; r < n; r += gridDim.x * 2) {
    float v = agg[(size_t)r * D + c];
    s += v;
    s2 += v * v;
  }
  atomicAdd(&sums[c], s);
  atomicAdd(&sums[D + c], s2);
}

__global__ void k_bn_fin(const float* __restrict__ sums, const float* __restrict__ gamma,
        const float* __restrict__ beta, float* __restrict__ ss, float inv_n) {
  int c = threadIdx.x;
  float mu = sums[c] * inv_n;
  float var = sums[D + c] * inv_n - mu * mu;
  float rs = rsqrtf(var + BN_EPS);
  float sc = gamma[c] * rs;
  ss[c] = sc;
  ss[D + c] = beta[c] - mu * sc;
}

__global__ __launch_bounds__(256) void k_bn_apply(const float* __restrict__ agg,
        const float* __restrict__ ss, float* __restrict__ xo, int total4) {
  int i = blockIdx.x * 256 + threadIdx.x;
  if (i >= total4) return;
  float4 v = ((const float4*)agg)[i];
  int c4 = i & (D / 4 - 1);
  float4 sc = ((const float4*)ss)[c4];
  float4 sh = ((const float4*)ss)[D / 4 + c4];
  float y0 = sc.x * v.x + sh.x;
  float y1 = sc.y * v.y + sh.y;
  float y2 = sc.z * v.z + sh.z;
  float y3 = sc.w * v.w + sh.w;
  float4 g;
  g.x = 0.5f * y0 * (1.f + erff(y0 * 0.70710678118654752f));
  g.y = 0.5f * y1 * (1.f + erff(y1 * 0.70710678118654752f));
  g.z = 0.5f * y2 * (1.f + erff(y2 * 0.70710678118654752f));
  g.w = 0.5f * y3 * (1.f + erff(y3 * 0.70710678118654752f));
  ((float4*)xo)[i] = g;
}

// ===========================================================================

extern "C" void kernel_launch(void* const* d_in, const int* in_sizes, int n_in,
                              void* d_out, int out_size, void* d_ws, size_t ws_size,
                              hipStream_t stream) {
  const float* x0    = (const float*)d_in[0];
  const int*   ei    = (const int*)d_in[1];
  const float* Wl    = (const float*)d_in[2];
  const float* Wr    = (const float*)d_in[3];
  const float* att   = (const float*)d_in[4];
  // d_in[5] = bias: cancelled exactly by BatchNorm mean-subtraction; unused.
  const float* gamma = (const float*)d_in[6];
  const float* beta  = (const float*)d_in[7];
  float* out = (float*)d_out;

  float* ws = (float*)d_ws;
  float* xl      = ws;                          // 6,400,000
  float* xr      = ws + 6400000;                // 6,400,000
  float* esc     = ws + 12800000;               //   800,000
  int*   col_src = (int*)(ws + 13600000);       //   800,000
  int*   col_dst = (int*)(ws + 14400000);       //   800,000
  int*   row_ptr = (int*)(ws + 15200000);       //    50,001
  int*   cursor  = (int*)(ws + 15250004);       //    50,000
  int*   counts  = (int*)(ws + 15300004);       //    50,000
  float* sums    = ws + 15350004;               //       256
  float* ss      = ws + 15350260;               //       256

  const int* src = ei;
  const int* dst = ei + NEDGES;

  // ---- build CSR by destination (once; reused for all 3 layers) ----
  hipMemsetAsync(counts, 0, NNODES * sizeof(int), stream);
  k_hist<<<(NEDGES + 255) / 256, 256, 0, stream>>>(dst, counts, NEDGES);
  k_scan<<<1, 256, 0, stream>>>(counts, row_ptr, NNODES);
  hipMemcpyAsync(cursor, row_ptr, NNODES * sizeof(int), hipMemcpyDeviceToDevice, stream);
  k_scatter<<<(NEDGES + 255) / 256, 256, 0, stream>>>(src, dst, cursor, col_src, col_dst, NEDGES);

  dim3 ggrid((NNODES + 63) / 64, 4);

  for (int l = 0; l < 3; ++l) {
    const float* xin = (l == 0) ? x0 : out;

    k_gemm<<<ggrid, 256, 0, stream>>>(xin, Wl + l * D * D, Wr + l * D * D,
                                      xl, xr, NNODES);
    hipMemsetAsync(sums, 0, 2 * D * sizeof(float), stream);

    k_edge_score<<<(NEDGES + 255) / 256, 256, 0, stream>>>(xl, xr, col_src, col_dst,
                                                           att + l * D, esc, NEDGES);
    // d_out is dead as an input after k_gemm -> safe to overwrite with agg.
    k_agg<<<(NNODES + 3) / 4, 256, 0, stream>>>(esc, xl, col_src, row_ptr, out, NNODES);

    k_bn_stats<<<512, 256, 0, stream>>>(out, sums, NNODES);
    k_bn_fin<<<1, D, 0, stream>>>(sums, gamma + l * D, beta + l * D, ss, 1.0f / NNODES);
    k_bn_apply<<<(NNODES * (D / 4) + 255) / 256, 256, 0, stream>>>(out, ss, out, NNODES * (D / 4));
  }
}

// Round 5
// 1143.649 us; speedup vs baseline: 15.5663x; 1.0850x over previous
//
#include <hip/hip_runtime.h>
#include <math.h>

#define NNODES 50000
#define NEDGES 800000
#define D 128
#define NEG_SLOPE 0.2f
#define BN_EPS 1e-5f
#define SCAN_THREADS 1024
#define SCAN_CH ((NNODES + SCAN_THREADS - 1) / SCAN_THREADS)   // 49

// ============ CSR build (once per call; edge_index is layer-invariant) ======

__global__ __launch_bounds__(256) void k_hist(const int* __restrict__ dst,
        int* __restrict__ counts, int E) {
  int e = blockIdx.x * 256 + threadIdx.x;
  if (e < E) atomicAdd(&counts[dst[e]], 1);
}

// Single-workgroup fused scan: counts -> row_ptr (inclusive, +[0]=0) and
// cursor (exclusive). One dispatch, no cross-block handoffs.
__global__ __launch_bounds__(1024) void k_scan_all(const int* __restrict__ counts,
        int* __restrict__ row_ptr, int* __restrict__ cursor, int n) {
  __shared__ int tsum[SCAN_THREADS];
  int t = threadIdx.x;
  int base = t * SCAN_CH;
  int s = 0;
  for (int k = 0; k < SCAN_CH; ++k) {
    int i = base + k;
    s += (i < n) ? counts[i] : 0;
  }
  tsum[t] = s;
  __syncthreads();
  for (int off = 1; off < SCAN_THREADS; off <<= 1) {
    int u = (t >= off) ? tsum[t - off] : 0;
    __syncthreads();
    tsum[t] += u;
    __syncthreads();
  }
  int run = tsum[t] - s;   // exclusive prefix of this thread's chunk
  for (int k = 0; k < SCAN_CH; ++k) {
    int i = base + k;
    if (i < n) {
      int c = counts[i];
      cursor[i] = run;
      run += c;
      row_ptr[i + 1] = run;
    }
  }
  if (t == 0) row_ptr[0] = 0;
}

__global__ __launch_bounds__(256) void k_scatter(const int* __restrict__ src,
        const int* __restrict__ dst, int* __restrict__ cursor,
        int* __restrict__ col_src, int* __restrict__ col_dst, int E) {
  int e = blockIdx.x * 256 + threadIdx.x;
  if (e >= E) return;
  int s = src[e], d = dst[e];
  int slot = atomicAdd(&cursor[d], 1);
  col_src[slot] = s;
  col_dst[slot] = d;
}

// ============ GEMM: LDS-tiled, register-blocked f32 ========================
__global__ __launch_bounds__(256) void k_gemm(const float* __restrict__ x,
        const float* __restrict__ Wl, const float* __restrict__ Wr,
        float* __restrict__ xl, float* __restrict__ xr, int n) {
  __shared__ float xs[64 * 128];
  __shared__ float wsd[128 * 64];
  const int t = threadIdx.x;
  const int row0 = blockIdx.x * 64;
  const int cb = blockIdx.y;
  const float* __restrict__ Wg = (cb < 2) ? Wl : Wr;
  float* __restrict__ outp = (cb < 2) ? xl : xr;
  const int cbase = (cb & 1) * 64;

  {
    int row = t >> 2, qr = t & 3;
    int grow = row0 + row;
    if (grow >= n) grow = n - 1;
    const float4* gp = (const float4*)(x + (size_t)grow * D + qr * 32);
#pragma unroll
    for (int m = 0; m < 8; ++m) {
      float4 v = gp[m];
      int byte = row * 512 + qr * 128 + m * 16;
      byte ^= (row & 7) << 4;
      *(float4*)((char*)xs + byte) = v;
    }
  }
  {
#pragma unroll
    for (int m = 0; m < 8; ++m) {
      int idx = m * 256 + t;
      int k = idx >> 4, c4 = idx & 15;
      float4 v = *(const float4*)(Wg + k * D + cbase + c4 * 4);
      *(float4*)((char*)wsd + k * 256 + c4 * 16) = v;
    }
  }
  __syncthreads();

  const int i = t & 15;
  const int j = t >> 4;
  float acc[4][4];
#pragma unroll
  for (int r = 0; r < 4; ++r)
#pragma unroll
    for (int c = 0; c < 4; ++c) acc[r][c] = 0.f;

  for (int kc = 0; kc < 32; ++kc) {
    float4 xv[4], wv[4];
#pragma unroll
    for (int rr = 0; rr < 4; ++rr) {
      int row = i + rr * 16;
      int byte = (row * 512 + kc * 16) ^ ((row & 7) << 4);
      xv[rr] = *(const float4*)((const char*)xs + byte);
    }
#pragma unroll
    for (int kk = 0; kk < 4; ++kk) {
      wv[kk] = *(const float4*)((const char*)wsd + (kc * 4 + kk) * 256 + j * 16);
    }
#pragma unroll
    for (int rr = 0; rr < 4; ++rr) {
      const float* xr_ = (const float*)&xv[rr];
#pragma unroll
      for (int kk = 0; kk < 4; ++kk) {
        const float* wr_ = (const float*)&wv[kk];
        float xk = xr_[kk];
        acc[rr][0] += xk * wr_[0];
        acc[rr][1] += xk * wr_[1];
        acc[rr][2] += xk * wr_[2];
        acc[rr][3] += xk * wr_[3];
      }
    }
  }

#pragma unroll
  for (int rr = 0; rr < 4; ++rr) {
    int grow = row0 + i + rr * 16;
    if (grow < n) {
      float4 v = make_float4(acc[rr][0], acc[rr][1], acc[rr][2], acc[rr][3]);
      *(float4*)(outp + (size_t)grow * D + cbase + j * 4) = v;
    }
  }
}

// ============ edge kernels =================================================

__global__ __launch_bounds__(256) void k_edge_score(const float* __restrict__ xl,
        const float* __restrict__ xr, const int* __restrict__ col_src,
        const int* __restrict__ col_dst, const float* __restrict__ att,
        float* __restrict__ esc, int E) {
  int e = blockIdx.x * 256 + threadIdx.x;
  if (e >= E) return;
  int s = col_src[e], d = col_dst[e];
  const float4* a4 = (const float4*)(xl + (size_t)s * D);
  const float4* b4 = (const float4*)(xr + (size_t)d * D);
  const float4* t4 = (const float4*)att;
  float acc = 0.f;
#pragma unroll
  for (int k = 0; k < D / 4; ++k) {
    float4 a = a4[k], b = b4[k], w = t4[k];
    float v0 = a.x + b.x; v0 = v0 > 0.f ? v0 : NEG_SLOPE * v0;
    float v1 = a.y + b.y; v1 = v1 > 0.f ? v1 : NEG_SLOPE * v1;
    float v2 = a.z + b.z; v2 = v2 > 0.f ? v2 : NEG_SLOPE * v2;
    float v3 = a.w + b.w; v3 = v3 > 0.f ? v3 : NEG_SLOPE * v3;
    acc += v0 * w.x + v1 * w.y + v2 * w.z + v3 * w.w;
  }
  esc[e] = acc;
}

__global__ __launch_bounds__(256) void k_agg(const float* __restrict__ esc,
        const float* __restrict__ xl, const int* __restrict__ col_src,
        const int* __restrict__ row_ptr, float* __restrict__ out, int n) {
  int node = blockIdx.x * 4 + (threadIdx.x >> 6);
  if (node >= n) return;
  int c = threadIdx.x & 63;
  int k0 = row_ptr[node], k1 = row_ptr[node + 1];
  float m = -1e30f;
  for (int k = k0; k < k1; ++k) m = fmaxf(m, esc[k]);
  float ax = 0.f, ay = 0.f, den = 0.f;
  const float2* xl2 = (const float2*)xl;
  for (int k = k0; k < k1; ++k) {
    float a = __expf(esc[k] - m);
    den += a;
    int s = col_src[k];
    float2 v = xl2[(size_t)s * (D / 2) + c];
    ax += a * v.x;
    ay += a * v.y;
  }
  float inv = 1.f / (den + 1e-16f);
  ((float2*)out)[(size_t)node * (D / 2) + c] = make_float2(ax * inv, ay * inv);
}

// ============ BatchNorm + GELU =============================================

__global__ __launch_bounds__(256) void k_bn_stats(const float* __restrict__ agg,
        float* __restrict__ sums, int n) {
  int c = threadIdx.x & 127;
  int half = threadIdx.x >> 7;
  float s = 0.f, s2 = 0.f;
  for (int r = blockIdx.x * 2 + half; r < n; r += gridDim.x * 2) {
    float v = agg[(size_t)r * D + c];
    s += v;
    s2 += v * v;
  }
  atomicAdd(&sums[c], s);
  atomicAdd(&sums[D + c], s2);
}

__global__ void k_bn_fin(const float* __restrict__ sums, const float* __restrict__ gamma,
        const float* __restrict__ beta, float* __restrict__ ss, float inv_n) {
  int c = threadIdx.x;
  float mu = sums[c] * inv_n;
  float var = sums[D + c] * inv_n - mu * mu;
  float rs = rsqrtf(var + BN_EPS);
  float sc = gamma[c] * rs;
  ss[c] = sc;
  ss[D + c] = beta[c] - mu * sc;
}

__global__ __launch_bounds__(256) void k_bn_apply(const float* __restrict__ agg,
        const float* __restrict__ ss, float* __restrict__ xo, int total4) {
  int i = blockIdx.x * 256 + threadIdx.x;
  if (i >= total4) return;
  float4 v = ((const float4*)agg)[i];
  int c4 = i & (D / 4 - 1);
  float4 sc = ((const float4*)ss)[c4];
  float4 sh = ((const float4*)ss)[D / 4 + c4];
  float y0 = sc.x * v.x + sh.x;
  float y1 = sc.y * v.y + sh.y;
  float y2 = sc.z * v.z + sh.z;
  float y3 = sc.w * v.w + sh.w;
  float4 g;
  g.x = 0.5f * y0 * (1.f + erff(y0 * 0.70710678118654752f));
  g.y = 0.5f * y1 * (1.f + erff(y1 * 0.70710678118654752f));
  g.z = 0.5f * y2 * (1.f + erff(y2 * 0.70710678118654752f));
  g.w = 0.5f * y3 * (1.f + erff(y3 * 0.70710678118654752f));
  ((float4*)xo)[i] = g;
}

// ===========================================================================

extern "C" void kernel_launch(void* const* d_in, const int* in_sizes, int n_in,
                              void* d_out, int out_size, void* d_ws, size_t ws_size,
                              hipStream_t stream) {
  const float* x0    = (const float*)d_in[0];
  const int*   ei    = (const int*)d_in[1];
  const float* Wl    = (const float*)d_in[2];
  const float* Wr    = (const float*)d_in[3];
  const float* att   = (const float*)d_in[4];
  // d_in[5] = bias: cancelled exactly by BatchNorm mean-subtraction; unused.
  const float* gamma = (const float*)d_in[6];
  const float* beta  = (const float*)d_in[7];
  float* out = (float*)d_out;

  float* ws = (float*)d_ws;
  float* xl      = ws;                          // 6,400,000
  float* xr      = ws + 6400000;                // 6,400,000
  float* esc     = ws + 12800000;               //   800,000
  int*   col_src = (int*)(ws + 13600000);       //   800,000
  int*   col_dst = (int*)(ws + 14400000);       //   800,000
  int*   row_ptr = (int*)(ws + 15200000);       //    50,001
  int*   cursor  = (int*)(ws + 15250004);       //    50,000
  int*   counts  = (int*)(ws + 15300004);       //    50,000
  float* sums    = ws + 15350004;               //       256
  float* ss      = ws + 15350260;               //       256

  const int* src = ei;
  const int* dst = ei + NEDGES;

  // ---- build CSR by destination (once; reused for all 3 layers) ----
  hipMemsetAsync(counts, 0, NNODES * sizeof(int), stream);
  k_hist<<<(NEDGES + 255) / 256, 256, 0, stream>>>(dst, counts, NEDGES);
  k_scan_all<<<1, SCAN_THREADS, 0, stream>>>(counts, row_ptr, cursor, NNODES);
  k_scatter<<<(NEDGES + 255) / 256, 256, 0, stream>>>(src, dst, cursor, col_src, col_dst, NEDGES);

  dim3 ggrid((NNODES + 63) / 64, 4);

  for (int l = 0; l < 3; ++l) {
    const float* xin = (l == 0) ? x0 : out;

    k_gemm<<<ggrid, 256, 0, stream>>>(xin, Wl + l * D * D, Wr + l * D * D,
                                      xl, xr, NNODES);
    hipMemsetAsync(sums, 0, 2 * D * sizeof(float), stream);

    k_edge_score<<<(NEDGES + 255) / 256, 256, 0, stream>>>(xl, xr, col_src, col_dst,
                                                           att + l * D, esc, NEDGES);
    // d_out is dead as an input after k_gemm -> safe to overwrite with agg.
    k_agg<<<(NNODES + 3) / 4, 256, 0, stream>>>(esc, xl, col_src, row_ptr, out, NNODES);

    k_bn_stats<<<512, 256, 0, stream>>>(out, sums, NNODES);
    k_bn_fin<<<1, D, 0, stream>>>(sums, gamma + l * D, beta + l * D, ss, 1.0f / NNODES);
    k_bn_apply<<<(NNODES * (D / 4) + 255) / 256, 256, 0, stream>>>(out, ss, out, NNODES * (D / 4));
  }
}

// Round 6
// 982.478 us; speedup vs baseline: 18.1199x; 1.1640x over previous
//
#include <hip/hip_runtime.h>
#include <math.h>

#define NNODES 50000
#define NEDGES 800000
#define D 128
#define NEG_SLOPE 0.2f
#define BN_EPS 1e-5f
#define SCAN_THREADS 1024
#define SCAN_CH 52                       // 13 x int4 per thread
#define COUNTS_PAD (SCAN_THREADS * SCAN_CH)   // 53248 >= 50000

// ============ CSR build (once per call; edge_index is layer-invariant) ======

__global__ __launch_bounds__(256) void k_hist(const int* __restrict__ dst,
        int* __restrict__ counts, int E) {
  int e = blockIdx.x * 256 + threadIdx.x;
  if (e < E) atomicAdd(&counts[dst[e]], 1);
}

// Single-workgroup fused scan, register-resident.
// Each thread: 13 int4 loads (in flight together), reg sum, 1024-wide LDS scan,
// then emit cursor (exclusive) and row_ptr (inclusive) from registers.
__global__ __launch_bounds__(1024) void k_scan_all(const int* __restrict__ counts,
        int* __restrict__ row_ptr, int* __restrict__ cursor, int n) {
  __shared__ int tsum[SCAN_THREADS];
  int t = threadIdx.x;
  int4 c[13];
  const int4* c4 = (const int4*)(counts + t * SCAN_CH);
  int s = 0;
#pragma unroll
  for (int k = 0; k < 13; ++k) {
    c[k] = c4[k];
    s += c[k].x + c[k].y + c[k].z + c[k].w;
  }
  tsum[t] = s;
  __syncthreads();
  for (int off = 1; off < SCAN_THREADS; off <<= 1) {
    int u = (t >= off) ? tsum[t - off] : 0;
    __syncthreads();
    tsum[t] += u;
    __syncthreads();
  }
  int run = tsum[t] - s;   // exclusive prefix of this thread's chunk
  int base = t * SCAN_CH;
#pragma unroll
  for (int k = 0; k < 13; ++k) {
    int i = base + k * 4;
    int4 v = c[k];
    if (i     < n) { cursor[i]     = run; run += v.x; row_ptr[i + 1] = run; }
    if (i + 1 < n) { cursor[i + 1] = run; run += v.y; row_ptr[i + 2] = run; }
    if (i + 2 < n) { cursor[i + 2] = run; run += v.z; row_ptr[i + 3] = run; }
    if (i + 3 < n) { cursor[i + 3] = run; run += v.w; row_ptr[i + 4] = run; }
  }
  if (t == 0) row_ptr[0] = 0;
}

__global__ __launch_bounds__(256) void k_scatter(const int* __restrict__ src,
        const int* __restrict__ dst, int* __restrict__ cursor,
        int* __restrict__ col_src, int* __restrict__ col_dst, int E) {
  int e = blockIdx.x * 256 + threadIdx.x;
  if (e >= E) return;
  int s = src[e], d = dst[e];
  int slot = atomicAdd(&cursor[d], 1);
  col_src[slot] = s;
  col_dst[slot] = d;
}

// ============ GEMM: LDS-tiled, register-blocked f32 ========================
__global__ __launch_bounds__(256) void k_gemm(const float* __restrict__ x,
        const float* __restrict__ Wl, const float* __restrict__ Wr,
        float* __restrict__ xl, float* __restrict__ xr, int n) {
  __shared__ float xs[64 * 128];
  __shared__ float wsd[128 * 64];
  const int t = threadIdx.x;
  const int row0 = blockIdx.x * 64;
  const int cb = blockIdx.y;
  const float* __restrict__ Wg = (cb < 2) ? Wl : Wr;
  float* __restrict__ outp = (cb < 2) ? xl : xr;
  const int cbase = (cb & 1) * 64;

  {
    int row = t >> 2, qr = t & 3;
    int grow = row0 + row;
    if (grow >= n) grow = n - 1;
    const float4* gp = (const float4*)(x + (size_t)grow * D + qr * 32);
#pragma unroll
    for (int m = 0; m < 8; ++m) {
      float4 v = gp[m];
      int byte = row * 512 + qr * 128 + m * 16;
      byte ^= (row & 7) << 4;
      *(float4*)((char*)xs + byte) = v;
    }
  }
  {
#pragma unroll
    for (int m = 0; m < 8; ++m) {
      int idx = m * 256 + t;
      int k = idx >> 4, c4 = idx & 15;
      float4 v = *(const float4*)(Wg + k * D + cbase + c4 * 4);
      *(float4*)((char*)wsd + k * 256 + c4 * 16) = v;
    }
  }
  __syncthreads();

  const int i = t & 15;
  const int j = t >> 4;
  float acc[4][4];
#pragma unroll
  for (int r = 0; r < 4; ++r)
#pragma unroll
    for (int c = 0; c < 4; ++c) acc[r][c] = 0.f;

  for (int kc = 0; kc < 32; ++kc) {
    float4 xv[4], wv[4];
#pragma unroll
    for (int rr = 0; rr < 4; ++rr) {
      int row = i + rr * 16;
      int byte = (row * 512 + kc * 16) ^ ((row & 7) << 4);
      xv[rr] = *(const float4*)((const char*)xs + byte);
    }
#pragma unroll
    for (int kk = 0; kk < 4; ++kk) {
      wv[kk] = *(const float4*)((const char*)wsd + (kc * 4 + kk) * 256 + j * 16);
    }
#pragma unroll
    for (int rr = 0; rr < 4; ++rr) {
      const float* xr_ = (const float*)&xv[rr];
#pragma unroll
      for (int kk = 0; kk < 4; ++kk) {
        const float* wr_ = (const float*)&wv[kk];
        float xk = xr_[kk];
        acc[rr][0] += xk * wr_[0];
        acc[rr][1] += xk * wr_[1];
        acc[rr][2] += xk * wr_[2];
        acc[rr][3] += xk * wr_[3];
      }
    }
  }

#pragma unroll
  for (int rr = 0; rr < 4; ++rr) {
    int grow = row0 + i + rr * 16;
    if (grow < n) {
      float4 v = make_float4(acc[rr][0], acc[rr][1], acc[rr][2], acc[rr][3]);
      *(float4*)(outp + (size_t)grow * D + cbase + j * 4) = v;
    }
  }
}

// ============ edge kernels =================================================

// quad-per-edge score: 4 lanes cooperate on one edge; each iteration the quad
// reads one contiguous 64B chunk of xl[src] and xr[dst] -> full L1-line use.
// Dot reduced across the quad with 2 shfl_xor steps; lane 0 writes.
__global__ __launch_bounds__(256) void k_edge_score(const float* __restrict__ xl,
        const float* __restrict__ xr, const int* __restrict__ col_src,
        const int* __restrict__ col_dst, const float* __restrict__ att,
        float* __restrict__ esc, int E) {
  int e = blockIdx.x * 64 + (threadIdx.x >> 2);
  if (e >= E) return;
  int ql = threadIdx.x & 3;
  int s = col_src[e], d = col_dst[e];
  const float4* a4 = (const float4*)(xl + (size_t)s * D);
  const float4* b4 = (const float4*)(xr + (size_t)d * D);
  const float4* t4 = (const float4*)att;
  float acc = 0.f;
#pragma unroll
  for (int i = 0; i < 8; ++i) {
    int q = i * 4 + ql;
    float4 a = a4[q], b = b4[q], w = t4[q];
    float v0 = a.x + b.x; v0 = v0 > 0.f ? v0 : NEG_SLOPE * v0;
    float v1 = a.y + b.y; v1 = v1 > 0.f ? v1 : NEG_SLOPE * v1;
    float v2 = a.z + b.z; v2 = v2 > 0.f ? v2 : NEG_SLOPE * v2;
    float v3 = a.w + b.w; v3 = v3 > 0.f ? v3 : NEG_SLOPE * v3;
    acc += v0 * w.x + v1 * w.y + v2 * w.z + v3 * w.w;
  }
  acc += __shfl_xor(acc, 1);
  acc += __shfl_xor(acc, 2);
  if (ql == 0) esc[e] = acc;
}

__global__ __launch_bounds__(256) void k_agg(const float* __restrict__ esc,
        const float* __restrict__ xl, const int* __restrict__ col_src,
        const int* __restrict__ row_ptr, float* __restrict__ out, int n) {
  int node = blockIdx.x * 4 + (threadIdx.x >> 6);
  if (node >= n) return;
  int c = threadIdx.x & 63;
  int k0 = row_ptr[node], k1 = row_ptr[node + 1];
  float m = -1e30f;
  for (int k = k0; k < k1; ++k) m = fmaxf(m, esc[k]);
  float ax = 0.f, ay = 0.f, den = 0.f;
  const float2* xl2 = (const float2*)xl;
  for (int k = k0; k < k1; ++k) {
    float a = __expf(esc[k] - m);
    den += a;
    int s = col_src[k];
    float2 v = xl2[(size_t)s * (D / 2) + c];
    ax += a * v.x;
    ay += a * v.y;
  }
  float inv = 1.f / (den + 1e-16f);
  ((float2*)out)[(size_t)node * (D / 2) + c] = make_float2(ax * inv, ay * inv);
}

// ============ BatchNorm + GELU =============================================

__global__ __launch_bounds__(256) void k_bn_stats(const float* __restrict__ agg,
        float* __restrict__ sums, int n) {
  int c = threadIdx.x & 127;
  int half = threadIdx.x >> 7;
  float s = 0.f, s2 = 0.f;
  for (int r = blockIdx.x * 2 + half; r < n; r += gridDim.x * 2) {
    float v = agg[(size_t)r * D + c];
    s += v;
    s2 += v * v;
  }
  atomicAdd(&sums[c], s);
  atomicAdd(&sums[D + c], s2);
}

__global__ void k_bn_fin(const float* __restrict__ sums, const float* __restrict__ gamma,
        const float* __restrict__ beta, float* __restrict__ ss, float inv_n) {
  int c = threadIdx.x;
  float mu = sums[c] * inv_n;
  float var = sums[D + c] * inv_n - mu * mu;
  float rs = rsqrtf(var + BN_EPS);
  float sc = gamma[c] * rs;
  ss[c] = sc;
  ss[D + c] = beta[c] - mu * sc;
}

__global__ __launch_bounds__(256) void k_bn_apply(const float* __restrict__ agg,
        const float* __restrict__ ss, float* __restrict__ xo, int total4) {
  int i = blockIdx.x * 256 + threadIdx.x;
  if (i >= total4) return;
  float4 v = ((const float4*)agg)[i];
  int c4 = i & (D / 4 - 1);
  float4 sc = ((const float4*)ss)[c4];
  float4 sh = ((const float4*)ss)[D / 4 + c4];
  float y0 = sc.x * v.x + sh.x;
  float y1 = sc.y * v.y + sh.y;
  float y2 = sc.z * v.z + sh.z;
  float y3 = sc.w * v.w + sh.w;
  float4 g;
  g.x = 0.5f * y0 * (1.f + erff(y0 * 0.70710678118654752f));
  g.y = 0.5f * y1 * (1.f + erff(y1 * 0.70710678118654752f));
  g.z = 0.5f * y2 * (1.f + erff(y2 * 0.70710678118654752f));
  g.w = 0.5f * y3 * (1.f + erff(y3 * 0.70710678118654752f));
  ((float4*)xo)[i] = g;
}

// ===========================================================================

extern "C" void kernel_launch(void* const* d_in, const int* in_sizes, int n_in,
                              void* d_out, int out_size, void* d_ws, size_t ws_size,
                              hipStream_t stream) {
  const float* x0    = (const float*)d_in[0];
  const int*   ei    = (const int*)d_in[1];
  const float* Wl    = (const float*)d_in[2];
  const float* Wr    = (const float*)d_in[3];
  const float* att   = (const float*)d_in[4];
  // d_in[5] = bias: cancelled exactly by BatchNorm mean-subtraction; unused.
  const float* gamma = (const float*)d_in[6];
  const float* beta  = (const float*)d_in[7];
  float* out = (float*)d_out;

  float* ws = (float*)d_ws;
  float* xl      = ws;                          // 6,400,000
  float* xr      = ws + 6400000;                // 6,400,000
  float* esc     = ws + 12800000;               //   800,000
  int*   col_src = (int*)(ws + 13600000);       //   800,000
  int*   col_dst = (int*)(ws + 14400000);       //   800,000
  int*   row_ptr = (int*)(ws + 15200000);       //    50,001
  int*   cursor  = (int*)(ws + 15250004);       //    50,000
  int*   counts  = (int*)(ws + 15300004);       // COUNTS_PAD (16B-aligned)
  float* sums    = ws + 15353252;               //       256
  float* ss      = ws + 15353508;               //       256

  const int* src = ei;
  const int* dst = ei + NEDGES;

  // ---- build CSR by destination (once; reused for all 3 layers) ----
  hipMemsetAsync(counts, 0, COUNTS_PAD * sizeof(int), stream);
  k_hist<<<(NEDGES + 255) / 256, 256, 0, stream>>>(dst, counts, NEDGES);
  k_scan_all<<<1, SCAN_THREADS, 0, stream>>>(counts, row_ptr, cursor, NNODES);
  k_scatter<<<(NEDGES + 255) / 256, 256, 0, stream>>>(src, dst, cursor, col_src, col_dst, NEDGES);

  dim3 ggrid((NNODES + 63) / 64, 4);

  for (int l = 0; l < 3; ++l) {
    const float* xin = (l == 0) ? x0 : out;

    k_gemm<<<ggrid, 256, 0, stream>>>(xin, Wl + l * D * D, Wr + l * D * D,
                                      xl, xr, NNODES);
    hipMemsetAsync(sums, 0, 2 * D * sizeof(float), stream);

    k_edge_score<<<(NEDGES + 63) / 64, 256, 0, stream>>>(xl, xr, col_src, col_dst,
                                                         att + l * D, esc, NEDGES);
    // d_out is dead as an input after k_gemm -> safe to overwrite with agg.
    k_agg<<<(NNODES + 3) / 4, 256, 0, stream>>>(esc, xl, col_src, row_ptr, out, NNODES);

    k_bn_stats<<<512, 256, 0, stream>>>(out, sums, NNODES);
    k_bn_fin<<<1, D, 0, stream>>>(sums, gamma + l * D, beta + l * D, ss, 1.0f / NNODES);
    k_bn_apply<<<(NNODES * (D / 4) + 255) / 256, 256, 0, stream>>>(out, ss, out, NNODES * (D / 4));
  }
}

// Round 7
// 703.322 us; speedup vs baseline: 25.3119x; 1.3969x over previous
//
#include <hip/hip_runtime.h>
#include <math.h>

#define NNODES 50000
#define NEDGES 800000
#define D 128
#define NEG_SLOPE 0.2f
#define BN_EPS 1e-5f
#define SCAN_THREADS 1024
#define SCAN_CH 52                       // 13 x int4 per thread
#define COUNTS_PAD (SCAN_THREADS * SCAN_CH)   // 53248 >= 50000

// ============ CSR build (once per call; edge_index is layer-invariant) ======

__global__ __launch_bounds__(256) void k_hist(const int* __restrict__ dst,
        int* __restrict__ counts, int E) {
  int e = blockIdx.x * 256 + threadIdx.x;
  if (e < E) atomicAdd(&counts[dst[e]], 1);
}

// Single-workgroup fused scan, register-resident.
__global__ __launch_bounds__(1024) void k_scan_all(const int* __restrict__ counts,
        int* __restrict__ row_ptr, int* __restrict__ cursor, int n) {
  __shared__ int tsum[SCAN_THREADS];
  int t = threadIdx.x;
  int4 c[13];
  const int4* c4 = (const int4*)(counts + t * SCAN_CH);
  int s = 0;
#pragma unroll
  for (int k = 0; k < 13; ++k) {
    c[k] = c4[k];
    s += c[k].x + c[k].y + c[k].z + c[k].w;
  }
  tsum[t] = s;
  __syncthreads();
  for (int off = 1; off < SCAN_THREADS; off <<= 1) {
    int u = (t >= off) ? tsum[t - off] : 0;
    __syncthreads();
    tsum[t] += u;
    __syncthreads();
  }
  int run = tsum[t] - s;   // exclusive prefix of this thread's chunk
  int base = t * SCAN_CH;
#pragma unroll
  for (int k = 0; k < 13; ++k) {
    int i = base + k * 4;
    int4 v = c[k];
    if (i     < n) { cursor[i]     = run; run += v.x; row_ptr[i + 1] = run; }
    if (i + 1 < n) { cursor[i + 1] = run; run += v.y; row_ptr[i + 2] = run; }
    if (i + 2 < n) { cursor[i + 2] = run; run += v.z; row_ptr[i + 3] = run; }
    if (i + 3 < n) { cursor[i + 3] = run; run += v.w; row_ptr[i + 4] = run; }
  }
  if (t == 0) row_ptr[0] = 0;
}

// col_dst no longer needed (score is fused into k_agg) -> scatter src only.
__global__ __launch_bounds__(256) void k_scatter(const int* __restrict__ src,
        const int* __restrict__ dst, int* __restrict__ cursor,
        int* __restrict__ col_src, int E) {
  int e = blockIdx.x * 256 + threadIdx.x;
  if (e >= E) return;
  int slot = atomicAdd(&cursor[dst[e]], 1);
  col_src[slot] = src[e];
}

// ============ GEMM: LDS-tiled, register-blocked f32 ========================
__global__ __launch_bounds__(256) void k_gemm(const float* __restrict__ x,
        const float* __restrict__ Wl, const float* __restrict__ Wr,
        float* __restrict__ xl, float* __restrict__ xr, int n) {
  __shared__ float xs[64 * 128];
  __shared__ float wsd[128 * 64];
  const int t = threadIdx.x;
  const int row0 = blockIdx.x * 64;
  const int cb = blockIdx.y;
  const float* __restrict__ Wg = (cb < 2) ? Wl : Wr;
  float* __restrict__ outp = (cb < 2) ? xl : xr;
  const int cbase = (cb & 1) * 64;

  {
    int row = t >> 2, qr = t & 3;
    int grow = row0 + row;
    if (grow >= n) grow = n - 1;
    const float4* gp = (const float4*)(x + (size_t)grow * D + qr * 32);
#pragma unroll
    for (int m = 0; m < 8; ++m) {
      float4 v = gp[m];
      int byte = row * 512 + qr * 128 + m * 16;
      byte ^= (row & 7) << 4;
      *(float4*)((char*)xs + byte) = v;
    }
  }
  {
#pragma unroll
    for (int m = 0; m < 8; ++m) {
      int idx = m * 256 + t;
      int k = idx >> 4, c4 = idx & 15;
      float4 v = *(const float4*)(Wg + k * D + cbase + c4 * 4);
      *(float4*)((char*)wsd + k * 256 + c4 * 16) = v;
    }
  }
  __syncthreads();

  const int i = t & 15;
  const int j = t >> 4;
  float acc[4][4];
#pragma unroll
  for (int r = 0; r < 4; ++r)
#pragma unroll
    for (int c = 0; c < 4; ++c) acc[r][c] = 0.f;

  for (int kc = 0; kc < 32; ++kc) {
    float4 xv[4], wv[4];
#pragma unroll
    for (int rr = 0; rr < 4; ++rr) {
      int row = i + rr * 16;
      int byte = (row * 512 + kc * 16) ^ ((row & 7) << 4);
      xv[rr] = *(const float4*)((const char*)xs + byte);
    }
#pragma unroll
    for (int kk = 0; kk < 4; ++kk) {
      wv[kk] = *(const float4*)((const char*)wsd + (kc * 4 + kk) * 256 + j * 16);
    }
#pragma unroll
    for (int rr = 0; rr < 4; ++rr) {
      const float* xr_ = (const float*)&xv[rr];
#pragma unroll
      for (int kk = 0; kk < 4; ++kk) {
        const float* wr_ = (const float*)&wv[kk];
        float xk = xr_[kk];
        acc[rr][0] += xk * wr_[0];
        acc[rr][1] += xk * wr_[1];
        acc[rr][2] += xk * wr_[2];
        acc[rr][3] += xk * wr_[3];
      }
    }
  }

#pragma unroll
  for (int rr = 0; rr < 4; ++rr) {
    int grow = row0 + i + rr * 16;
    if (grow < n) {
      float4 v = make_float4(acc[rr][0], acc[rr][1], acc[rr][2], acc[rr][3]);
      *(float4*)(outp + (size_t)grow * D + cbase + j * 4) = v;
    }
  }
}

// ============ fused score + online-softmax + aggregate =====================
// One wave per node, float2/lane. Per edge: gather xl[src] row (512B/wave),
// score e = leaky_relu(xl+xr).att via 6-step shfl_xor butterfly (e uniform),
// online softmax (running max + uniform rescale), weighted accumulate.

__device__ __forceinline__ float edge_e(float2 v, float2 xrv, float2 attv) {
  float t0 = v.x + xrv.x; t0 = t0 > 0.f ? t0 : NEG_SLOPE * t0;
  float t1 = v.y + xrv.y; t1 = t1 > 0.f ? t1 : NEG_SLOPE * t1;
  float p = t0 * attv.x + t1 * attv.y;
  p += __shfl_xor(p, 1);
  p += __shfl_xor(p, 2);
  p += __shfl_xor(p, 4);
  p += __shfl_xor(p, 8);
  p += __shfl_xor(p, 16);
  p += __shfl_xor(p, 32);
  return p;
}

__device__ __forceinline__ void sm_upd(float e, float2 v, float& m, float& den,
                                       float& ax, float& ay) {
  if (e > m) {                      // wave-uniform branch
    float sc = __expf(m - e);
    den *= sc; ax *= sc; ay *= sc;
    m = e;
  }
  float a = __expf(e - m);
  den += a; ax += a * v.x; ay += a * v.y;
}

__global__ __launch_bounds__(256) void k_agg(const float* __restrict__ xl,
        const float* __restrict__ xr, const int* __restrict__ col_src,
        const int* __restrict__ row_ptr, const float* __restrict__ att,
        float* __restrict__ out, int n) {
  int node = blockIdx.x * 4 + (threadIdx.x >> 6);
  if (node >= n) return;
  int c = threadIdx.x & 63;
  const float2* xl2 = (const float2*)xl;
  float2 xrv  = ((const float2*)xr)[(size_t)node * (D / 2) + c];
  float2 attv = ((const float2*)att)[c];
  int k0 = row_ptr[node], k1 = row_ptr[node + 1];
  float m = -1e30f, den = 0.f, ax = 0.f, ay = 0.f;

  int k = k0;
  for (; k + 4 <= k1; k += 4) {
    int s0 = col_src[k], s1 = col_src[k + 1], s2 = col_src[k + 2], s3 = col_src[k + 3];
    float2 v0 = xl2[(size_t)s0 * (D / 2) + c];
    float2 v1 = xl2[(size_t)s1 * (D / 2) + c];
    float2 v2 = xl2[(size_t)s2 * (D / 2) + c];
    float2 v3 = xl2[(size_t)s3 * (D / 2) + c];
    float e0 = edge_e(v0, xrv, attv);
    float e1 = edge_e(v1, xrv, attv);
    float e2 = edge_e(v2, xrv, attv);
    float e3 = edge_e(v3, xrv, attv);
    sm_upd(e0, v0, m, den, ax, ay);
    sm_upd(e1, v1, m, den, ax, ay);
    sm_upd(e2, v2, m, den, ax, ay);
    sm_upd(e3, v3, m, den, ax, ay);
  }
  for (; k < k1; ++k) {
    int s = col_src[k];
    float2 v = xl2[(size_t)s * (D / 2) + c];
    float e = edge_e(v, xrv, attv);
    sm_upd(e, v, m, den, ax, ay);
  }

  float inv = 1.f / (den + 1e-16f);
  ((float2*)out)[(size_t)node * (D / 2) + c] = make_float2(ax * inv, ay * inv);
}

// ============ BatchNorm + GELU =============================================

__global__ __launch_bounds__(256) void k_bn_stats(const float* __restrict__ agg,
        float* __restrict__ sums, int n) {
  int c = threadIdx.x & 127;
  int half = threadIdx.x >> 7;
  float s = 0.f, s2 = 0.f;
  for (int r = blockIdx.x * 2 + half; r < n; r += gridDim.x * 2) {
    float v = agg[(size_t)r * D + c];
    s += v;
    s2 += v * v;
  }
  atomicAdd(&sums[c], s);
  atomicAdd(&sums[D + c], s2);
}

__global__ void k_bn_fin(const float* __restrict__ sums, const float* __restrict__ gamma,
        const float* __restrict__ beta, float* __restrict__ ss, float inv_n) {
  int c = threadIdx.x;
  float mu = sums[c] * inv_n;
  float var = sums[D + c] * inv_n - mu * mu;
  float rs = rsqrtf(var + BN_EPS);
  float sc = gamma[c] * rs;
  ss[c] = sc;
  ss[D + c] = beta[c] - mu * sc;
}

__global__ __launch_bounds__(256) void k_bn_apply(const float* __restrict__ agg,
        const float* __restrict__ ss, float* __restrict__ xo, int total4) {
  int i = blockIdx.x * 256 + threadIdx.x;
  if (i >= total4) return;
  float4 v = ((const float4*)agg)[i];
  int c4 = i & (D / 4 - 1);
  float4 sc = ((const float4*)ss)[c4];
  float4 sh = ((const float4*)ss)[D / 4 + c4];
  float y0 = sc.x * v.x + sh.x;
  float y1 = sc.y * v.y + sh.y;
  float y2 = sc.z * v.z + sh.z;
  float y3 = sc.w * v.w + sh.w;
  float4 g;
  g.x = 0.5f * y0 * (1.f + erff(y0 * 0.70710678118654752f));
  g.y = 0.5f * y1 * (1.f + erff(y1 * 0.70710678118654752f));
  g.z = 0.5f * y2 * (1.f + erff(y2 * 0.70710678118654752f));
  g.w = 0.5f * y3 * (1.f + erff(y3 * 0.70710678118654752f));
  ((float4*)xo)[i] = g;
}

// ===========================================================================

extern "C" void kernel_launch(void* const* d_in, const int* in_sizes, int n_in,
                              void* d_out, int out_size, void* d_ws, size_t ws_size,
                              hipStream_t stream) {
  const float* x0    = (const float*)d_in[0];
  const int*   ei    = (const int*)d_in[1];
  const float* Wl    = (const float*)d_in[2];
  const float* Wr    = (const float*)d_in[3];
  const float* att   = (const float*)d_in[4];
  // d_in[5] = bias: cancelled exactly by BatchNorm mean-subtraction; unused.
  const float* gamma = (const float*)d_in[6];
  const float* beta  = (const float*)d_in[7];
  float* out = (float*)d_out;

  float* ws = (float*)d_ws;
  float* xl      = ws;                          // 6,400,000
  float* xr      = ws + 6400000;                // 6,400,000
  int*   col_src = (int*)(ws + 12800000);       //   800,000
  int*   row_ptr = (int*)(ws + 13600000);       //    50,001
  int*   cursor  = (int*)(ws + 13650004);       //    50,000
  int*   counts  = (int*)(ws + 13700004);       // COUNTS_PAD (16B-aligned)
  float* sums    = ws + 13753252;               //       256
  float* ss      = ws + 13753508;               //       256

  const int* src = ei;
  const int* dst = ei + NEDGES;

  // ---- build CSR by destination (once; reused for all 3 layers) ----
  hipMemsetAsync(counts, 0, COUNTS_PAD * sizeof(int), stream);
  k_hist<<<(NEDGES + 255) / 256, 256, 0, stream>>>(dst, counts, NEDGES);
  k_scan_all<<<1, SCAN_THREADS, 0, stream>>>(counts, row_ptr, cursor, NNODES);
  k_scatter<<<(NEDGES + 255) / 256, 256, 0, stream>>>(src, dst, cursor, col_src, NEDGES);

  dim3 ggrid((NNODES + 63) / 64, 4);

  for (int l = 0; l < 3; ++l) {
    const float* xin = (l == 0) ? x0 : out;

    k_gemm<<<ggrid, 256, 0, stream>>>(xin, Wl + l * D * D, Wr + l * D * D,
                                      xl, xr, NNODES);
    hipMemsetAsync(sums, 0, 2 * D * sizeof(float), stream);

    // d_out is dead as an input after k_gemm -> safe to overwrite with agg.
    k_agg<<<(NNODES + 3) / 4, 256, 0, stream>>>(xl, xr, col_src, row_ptr,
                                                att + l * D, out, NNODES);

    k_bn_stats<<<512, 256, 0, stream>>>(out, sums, NNODES);
    k_bn_fin<<<1, D, 0, stream>>>(sums, gamma + l * D, beta + l * D, ss, 1.0f / NNODES);
    k_bn_apply<<<(NNODES * (D / 4) + 255) / 256, 256, 0, stream>>>(out, ss, out, NNODES * (D / 4));
  }
}